// Round 13
// baseline (108.035 us; speedup 1.0000x reference)
//
#include <hip/hip_runtime.h>

namespace {

constexpr int Cn   = 256;            // channels
constexpr int Hh   = 128;
constexpr int Ww   = 128;
constexpr int HW   = Hh * Ww;
constexpr int TILE = 16;             // spatial tile edge
constexpr int CCH  = 8;              // channels per LDS chunk
constexpr int NCH  = Cn / CCH;       // 32 chunks
constexpr int HALO = 4;
constexpr int X2T  = 24;             // x2 tile rows/cols staged
constexpr int X2S  = 48;             // padded row stride = 12 granules ->
                                     //  conflict-free b128 reads (r11: 8.26M->1.18M)
constexpr int X2CH = X2T * X2S;      // 1152 floats per channel
constexpr int SC4  = 6;              // float4 per staged row
constexpr int NF4  = CCH * X2T * SC4; // 1152 staged float4 = 2 * 576 exactly
constexpr int NOFF = 81;

// 576 threads = 9 waves; wave wv <-> window row di = wv (o = 9*wv + dj).
// Lane l: h = l>>2 (tile row), m = l&3 (cols 4m..4m+3).
// r13 = r12 + depth-2 staging pipeline: chunk k+1's loads are issued during
// phase k-1 and ds_written at the TOP of phase k (vmcnt wait ~free, a full
// phase of flight time), loads for k+2 issued right after. r12's counters:
// 7.6K cyc/phase vs 2.6K max pipe demand -- the fetch round-trip sat inside
// every phase. Staging is 2 float4/thread (granule-exact zero-fill).

__global__ __launch_bounds__(576, 1)
void costvol_kernel(const float* __restrict__ x1,
                    const float* __restrict__ x2,
                    float* __restrict__ out)
{
  __shared__ float s2[2][CCH * X2CH];   // 73,728 B (1 block/CU)

  const int t    = threadIdx.x;
  const int wv   = t >> 6;             // di = 0..8
  const int lane = t & 63;
  const int h    = lane >> 2;          // tile row 0..15
  const int m    = lane & 3;           // pixel group: cols 4m..4m+3

  const int tx = blockIdx.x, ty = blockIdx.y, b = blockIdx.z;
  const int x0 = tx * TILE, y0 = ty * TILE;

  const float* g1 = x1 + (size_t)b * Cn * HW + (size_t)(y0 + h) * Ww + (x0 + 4 * m);
  const float* g2 = x2 + (size_t)b * Cn * HW;

  // ---- float4-granular staging: slot j stages float4 f = t + 576*j ----
  // f -> ch = f/144, rem = f%144, row = rem/6, col4 = rem%6.
  // Halo granules are fully in- or out-of-range horizontally (x0%16==0,
  // gx = x0-4+4*col4 spans [-4..-1] or [128..131] when OOB) -> zero-fill
  // whole granule, matching the reference's zero padding.
  int  soff[2], swr[2];
  bool sval[2];
#pragma unroll
  for (int j = 0; j < 2; ++j) {
    const int f    = t + 576 * j;      // < 1152 always
    const int ch   = f / (X2T * SC4);
    const int rem  = f % (X2T * SC4);
    const int row  = rem / SC4, col4 = rem % SC4;
    const int gy = y0 - HALO + row;
    const int gx = x0 - HALO + 4 * col4;
    const bool ok = ((unsigned)gy < (unsigned)Hh) &&
                    (gx >= 0) && (gx + 3 < Ww + 1 + 3) && (gx + 3 <= Ww - 1 + 0 + 3) &&
                    (gx + 3 <= 127 + 3) && (gx <= Ww - 4 + 3) && (gx + 3 < Ww + 4) && (gx < Ww) && (gx >= 0);
    // simplified: granule valid iff 0 <= gx and gx+3 < Ww (gx is 4-aligned-ish,
    // halo granules are entirely out when gx<0 or gx>=Ww-3... see note above)
    sval[j] = ((unsigned)gy < (unsigned)Hh) && (gx >= 0) && (gx + 3 < Ww);
    soff[j] = sval[j] ? (ch * HW + gy * Ww + gx) : 0;
    swr[j]  = ch * X2CH + row * X2S + 4 * col4;
  }

  float4 rs[2][2];                     // [pipeline parity][slot]
  auto stage_load = [&](int k, int pr) {
    const size_t cb = (size_t)(k * CCH) * HW;
#pragma unroll
    for (int j = 0; j < 2; ++j)
      rs[pr][j] = sval[j] ? *reinterpret_cast<const float4*>(g2 + cb + soff[j])
                          : float4{0.f, 0.f, 0.f, 0.f};
  };
  auto stage_write = [&](int nb, int pr) {
    float* s = s2[nb];
#pragma unroll
    for (int j = 0; j < 2; ++j)
      *reinterpret_cast<float4*>(s + swr[j]) = rs[pr][j];
  };

  float acc[9][4];
#pragma unroll
  for (int d = 0; d < 9; ++d)
#pragma unroll
    for (int p = 0; p < 4; ++p) acc[d][p] = 0.0f;

  const int rbase = (h + wv) * X2S + 4 * m;

  // ---- batched half-chunk: load 4 channels' operands, then 144 FMAs ----
  auto half = [&](int k, int hc, const float* sc) {
    float4 a[4];
    float  w[4][12];
#pragma unroll
    for (int cc = 0; cc < 4; ++cc) {
      a[cc] = *reinterpret_cast<const float4*>(
          g1 + (size_t)(k * CCH + 4 * hc + cc) * HW);
      const float* bp = sc + (4 * hc + cc) * X2CH + rbase;
      *reinterpret_cast<float4*>(w[cc])     = *reinterpret_cast<const float4*>(bp);
      *reinterpret_cast<float4*>(w[cc] + 4) = *reinterpret_cast<const float4*>(bp + 4);
      *reinterpret_cast<float4*>(w[cc] + 8) = *reinterpret_cast<const float4*>(bp + 8);
    }
#pragma unroll
    for (int cc = 0; cc < 4; ++cc)
#pragma unroll
      for (int dj = 0; dj < 9; ++dj) {
        acc[dj][0] = fmaf(a[cc].x, w[cc][dj + 0], acc[dj][0]);
        acc[dj][1] = fmaf(a[cc].y, w[cc][dj + 1], acc[dj][1]);
        acc[dj][2] = fmaf(a[cc].z, w[cc][dj + 2], acc[dj][2]);
        acc[dj][3] = fmaf(a[cc].w, w[cc][dj + 3], acc[dj][3]);
      }
  };

  // ---- prologue: chunk0 staged+written, chunk1 loaded ----
  stage_load(0, 0);
  stage_write(0, 0);                   // waits chunk0 loads (once)
  stage_load(1, 1);
  __syncthreads();

  for (int k = 0; k < NCH; ++k) {
    const int pn = (k + 1) & 1;        // parity holding chunk k+1
    if (k + 1 < NCH) stage_write(pn, pn);   // top-of-phase write: loads from
                                            // phase k-1, vmcnt wait ~free
    if (k + 2 < NCH) stage_load(k + 2, k & 1);  // 2 phases of flight
    const float* sc = s2[k & 1];
    half(k, 0, sc);
    half(k, 1, sc);
    __syncthreads();
  }

  // ---- epilogue: o = 9*di + dj; each (b,o,y,x) written exactly once ----
  const float invc = 1.0f / (float)Cn;
  const int y  = y0 + h;
  const int xb = x0 + 4 * m;
#pragma unroll
  for (int dj = 0; dj < 9; ++dj) {
    const int o = wv * 9 + dj;
    float4 v;
    v.x = acc[dj][0] * invc;
    v.y = acc[dj][1] * invc;
    v.z = acc[dj][2] * invc;
    v.w = acc[dj][3] * invc;
    *reinterpret_cast<float4*>(out + (((size_t)b * NOFF + o) * Hh + y) * Ww + xb) = v;
  }
}

} // namespace

extern "C" void kernel_launch(void* const* d_in, const int* in_sizes, int n_in,
                              void* d_out, int out_size, void* d_ws, size_t ws_size,
                              hipStream_t stream) {
  const float* x1 = (const float*)d_in[0];
  const float* x2 = (const float*)d_in[1];
  float* out = (float*)d_out;

  dim3 grid(Ww / TILE, Hh / TILE, 4);   // 8 x 8 x 4 = 256 blocks (1/CU)
  dim3 block(576);                      // 9 waves: wave wv <-> window row di
  costvol_kernel<<<grid, block, 0, stream>>>(x1, x2, out);
}